// Round 1
// baseline (636.900 us; speedup 1.0000x reference)
//
#include <hip/hip_runtime.h>

// SPRTFlipLinear: y = x @ W^T, W = ternary * per-128-group scales.
// M=8192 (4*2048), N=OUT_F=4096, K=IN_F=4096. 274.9 GFLOP/call.
// Strategy: dequant W -> bf16 and cvt x -> bf16 in d_ws (memory-bound passes),
// then m97-style 128x128x64 bf16 MFMA GEMM with global_load_lds width=16.

#define IN_F  4096
#define OUT_F 4096
#define MROWS 8192
#define GROUP 128

#define BM 128
#define BN 128
#define BK 64

using bf16x8 = __attribute__((ext_vector_type(8))) __bf16;
using f32x4  = __attribute__((ext_vector_type(4))) float;

#define GLOBAL_AS __attribute__((address_space(1)))
#define LDS_AS    __attribute__((address_space(3)))

__device__ __forceinline__ unsigned short f2bf(float f) {
  // round-to-nearest-even fp32 -> bf16 (no NaN handling needed; inputs finite)
  unsigned int u = __float_as_uint(f);
  u += 0x7fffu + ((u >> 16) & 1u);
  return (unsigned short)(u >> 16);
}

// x fp32 -> bf16, 8 elements per thread (exact multiple: 33.5M/8/256 = 16384 blocks)
__global__ void cvt_x_kernel(const float* __restrict__ x, unsigned short* __restrict__ xb) {
  const int i = (blockIdx.x * 256 + threadIdx.x) * 8;
  const float4 a = *(const float4*)(x + i);
  const float4 b = *(const float4*)(x + i + 4);
  union { unsigned short u[8]; uint4 v; } o;
  o.u[0] = f2bf(a.x); o.u[1] = f2bf(a.y); o.u[2] = f2bf(a.z); o.u[3] = f2bf(a.w);
  o.u[4] = f2bf(b.x); o.u[5] = f2bf(b.y); o.u[6] = f2bf(b.z); o.u[7] = f2bf(b.w);
  *(uint4*)(xb + i) = o.v;
}

// ternary(int32 {-1,0,1}) * group scale -> bf16 W[OUT_F][IN_F]
// groups are 128-contiguous in flat (o*IN_F + i) order; 8 elems/thread stay in one group.
__global__ void dequant_w_kernel(const int* __restrict__ t, const float* __restrict__ s,
                                 unsigned short* __restrict__ wb) {
  const int i = (blockIdx.x * 256 + threadIdx.x) * 8;
  const float sc = s[i >> 7];  // GROUP=128
  const int4 t0 = *(const int4*)(t + i);
  const int4 t1 = *(const int4*)(t + i + 4);
  union { unsigned short u[8]; uint4 v; } o;
  o.u[0] = f2bf((float)t0.x * sc); o.u[1] = f2bf((float)t0.y * sc);
  o.u[2] = f2bf((float)t0.z * sc); o.u[3] = f2bf((float)t0.w * sc);
  o.u[4] = f2bf((float)t1.x * sc); o.u[5] = f2bf((float)t1.y * sc);
  o.u[6] = f2bf((float)t1.z * sc); o.u[7] = f2bf((float)t1.w * sc);
  *(uint4*)(wb + i) = o.v;
}

// C[M][N] = A[M][K] * B[N][K]^T, all bf16 inputs, fp32 out.
// 128x128 block tile, BK=64, 256 threads (4 waves, 2x2 wave grid, 64x64 per wave,
// 4x4 of 16x16x32 MFMA per wave). global_load_lds dwordx4 staging.
__global__ __launch_bounds__(256) void gemm_bt_kernel(const unsigned short* __restrict__ A,
                                                      const unsigned short* __restrict__ B,
                                                      float* __restrict__ C) {
  __shared__ unsigned short As[BM * BK];  // 16 KB, row-major [row][k], NO padding
  __shared__ unsigned short Bs[BN * BK];  // 16 KB

  const int tid  = threadIdx.x;
  const int lane = tid & 63;
  const int wv   = tid >> 6;
  const int wm   = wv & 1;       // wave m index (0..1)
  const int wn   = wv >> 1;      // wave n index (0..1)
  const int lr   = lane & 15;    // fragment row/col within 16
  const int quad = lane >> 4;    // 0..3

  const int m0 = blockIdx.y * BM;
  const int n0 = blockIdx.x * BN;

  // staging: chunk = 1024B = 8 rows of 64 bf16; 16 chunks total, 4 per wave.
  const int srow = lane >> 3;          // 0..7 row within chunk
  const int scol = (lane & 7) * 8;     // bf16 col (8 lanes x 16B = one 128B row)

  f32x4 acc[4][4];
#pragma unroll
  for (int i = 0; i < 4; ++i)
#pragma unroll
    for (int j = 0; j < 4; ++j)
      acc[i][j] = (f32x4)(0.0f);

  for (int k0 = 0; k0 < IN_F; k0 += BK) {
#pragma unroll
    for (int i = 0; i < 4; ++i) {
      const int chunk = wv * 4 + i;          // wave-uniform
      const int row   = chunk * 8 + srow;    // 0..127
      const unsigned short* ga = A + (size_t)(m0 + row) * IN_F + (k0 + scol);
      const unsigned short* gb = B + (size_t)(n0 + row) * IN_F + (k0 + scol);
      // dest = wave-uniform LDS base + lane*16 (HW behavior); layout matches.
      __builtin_amdgcn_global_load_lds((const GLOBAL_AS unsigned int*)ga,
                                       (LDS_AS unsigned int*)(As + chunk * 512),
                                       16, 0, 0);
      __builtin_amdgcn_global_load_lds((const GLOBAL_AS unsigned int*)gb,
                                       (LDS_AS unsigned int*)(Bs + chunk * 512),
                                       16, 0, 0);
    }
    __syncthreads();  // drains vmcnt (compiler emits waitcnt before s_barrier)

#pragma unroll
    for (int ks = 0; ks < BK; ks += 32) {
      bf16x8 af[4], bfr[4];
#pragma unroll
      for (int i = 0; i < 4; ++i) {
        // A frag: m = lr, k = quad*8 + j  -> contiguous 8 bf16 = ds_read_b128
        af[i]  = *(const bf16x8*)(As + (wm * 64 + i * 16 + lr) * BK + ks + quad * 8);
        // B frag (B^T rows): n = lr, k = quad*8 + j
        bfr[i] = *(const bf16x8*)(Bs + (wn * 64 + i * 16 + lr) * BK + ks + quad * 8);
      }
#pragma unroll
      for (int i = 0; i < 4; ++i)
#pragma unroll
        for (int j = 0; j < 4; ++j)
          acc[i][j] = __builtin_amdgcn_mfma_f32_16x16x32_bf16(af[i], bfr[j], acc[i][j], 0, 0, 0);
    }
    __syncthreads();
  }

  // epilogue: C/D layout col = lane&15, row = quad*4 + reg (m89/m91-verified)
#pragma unroll
  for (int i = 0; i < 4; ++i) {
    const int mrow = m0 + wm * 64 + i * 16 + quad * 4;
#pragma unroll
    for (int j = 0; j < 4; ++j) {
      const int ncol = n0 + wn * 64 + j * 16 + lr;
      float* cp = C + (size_t)mrow * OUT_F + ncol;
#pragma unroll
      for (int r = 0; r < 4; ++r)
        cp[(size_t)r * OUT_F] = acc[i][j][r];
    }
  }
}

extern "C" void kernel_launch(void* const* d_in, const int* in_sizes, int n_in,
                              void* d_out, int out_size, void* d_ws, size_t ws_size,
                              hipStream_t stream) {
  const float* x       = (const float*)d_in[0];   // [4,2048,4096] f32
  const int*   ternary = (const int*)d_in[1];     // [4096,4096] int (values -1,0,1)
  const float* scales  = (const float*)d_in[2];   // [131072] f32
  float* out = (float*)d_out;                     // [4,2048,4096] f32

  // workspace: x_bf16 (67.1 MB) then W_bf16 (33.6 MB) = 100.7 MB total
  unsigned short* xb = (unsigned short*)d_ws;
  unsigned short* wb = xb + (size_t)MROWS * IN_F;

  cvt_x_kernel<<<(MROWS * IN_F) / 8 / 256, 256, 0, stream>>>(x, xb);
  dequant_w_kernel<<<(OUT_F * IN_F) / 8 / 256, 256, 0, stream>>>(ternary, scales, wb);

  dim3 grid(OUT_F / BN, MROWS / BM);  // (32, 64) = 2048 blocks
  gemm_bt_kernel<<<grid, 256, 0, stream>>>(xb, wb, out);
}

// Round 2
// 602.349 us; speedup vs baseline: 1.0574x; 1.0574x over previous
//
#include <hip/hip_runtime.h>

// SPRTFlipLinear: y = x @ W^T, W = ternary * per-128-group scales.
// M=8192 (4*2048), N=OUT_F=4096, K=IN_F=4096. 274.9 GFLOP/call.
// R1: XOR-swizzled LDS layout to kill 16-way bank conflicts
//     (R0 measured SQ_LDS_BANK_CONFLICT=1.0e8 ~= 38% of GEMM cycles).

#define IN_F  4096
#define OUT_F 4096
#define MROWS 8192
#define GROUP 128

#define BM 128
#define BN 128
#define BK 64

using bf16x8 = __attribute__((ext_vector_type(8))) __bf16;
using f32x4  = __attribute__((ext_vector_type(4))) float;

#define GLOBAL_AS __attribute__((address_space(1)))
#define LDS_AS    __attribute__((address_space(3)))

__device__ __forceinline__ unsigned short f2bf(float f) {
  // round-to-nearest-even fp32 -> bf16 (inputs finite)
  unsigned int u = __float_as_uint(f);
  u += 0x7fffu + ((u >> 16) & 1u);
  return (unsigned short)(u >> 16);
}

// x fp32 -> bf16, 8 elements per thread
__global__ void cvt_x_kernel(const float* __restrict__ x, unsigned short* __restrict__ xb) {
  const int i = (blockIdx.x * 256 + threadIdx.x) * 8;
  const float4 a = *(const float4*)(x + i);
  const float4 b = *(const float4*)(x + i + 4);
  union { unsigned short u[8]; uint4 v; } o;
  o.u[0] = f2bf(a.x); o.u[1] = f2bf(a.y); o.u[2] = f2bf(a.z); o.u[3] = f2bf(a.w);
  o.u[4] = f2bf(b.x); o.u[5] = f2bf(b.y); o.u[6] = f2bf(b.z); o.u[7] = f2bf(b.w);
  *(uint4*)(xb + i) = o.v;
}

// ternary(int32 {-1,0,1}) * group scale -> bf16 W[OUT_F][IN_F]
__global__ void dequant_w_kernel(const int* __restrict__ t, const float* __restrict__ s,
                                 unsigned short* __restrict__ wb) {
  const int i = (blockIdx.x * 256 + threadIdx.x) * 8;
  const float sc = s[i >> 7];  // GROUP=128
  const int4 t0 = *(const int4*)(t + i);
  const int4 t1 = *(const int4*)(t + i + 4);
  union { unsigned short u[8]; uint4 v; } o;
  o.u[0] = f2bf((float)t0.x * sc); o.u[1] = f2bf((float)t0.y * sc);
  o.u[2] = f2bf((float)t0.z * sc); o.u[3] = f2bf((float)t0.w * sc);
  o.u[4] = f2bf((float)t1.x * sc); o.u[5] = f2bf((float)t1.y * sc);
  o.u[6] = f2bf((float)t1.z * sc); o.u[7] = f2bf((float)t1.w * sc);
  *(uint4*)(wb + i) = o.v;
}

// C[M][N] = A[M][K] * B[N][K]^T, bf16 in, fp32 out.
// 128x128 tile, BK=64, 256 threads (2x2 waves, 64x64/wave, 4x4 16x16x32 MFMA).
// LDS layout XOR-swizzled: 16B chunk kc of row r lives at physical chunk kc^(r&7).
// Staging realizes the swizzle by permuting per-lane GLOBAL source (LDS dest of
// global_load_lds is fixed base+lane*16); ds_read applies kc^(lr&7).
__global__ __launch_bounds__(256) void gemm_bt_kernel(const unsigned short* __restrict__ A,
                                                      const unsigned short* __restrict__ B,
                                                      float* __restrict__ C) {
  __shared__ unsigned short As[BM * BK];  // 16 KB
  __shared__ unsigned short Bs[BN * BK];  // 16 KB

  const int tid  = threadIdx.x;
  const int lane = tid & 63;
  const int wv   = tid >> 6;
  const int wm   = wv & 1;
  const int wn   = wv >> 1;
  const int lr   = lane & 15;
  const int quad = lane >> 4;

  const int m0 = blockIdx.y * BM;
  const int n0 = blockIdx.x * BN;

  // staging: chunk = 1024B = 8 rows x 128B; lane's LDS slot = (row srow, col lane&7).
  // swizzle: that slot must hold global k-chunk (lane&7) ^ srow.
  const int srow = lane >> 3;                       // 0..7 row within chunk
  const int scol = (((lane & 7) ^ srow)) * 8;       // permuted bf16 col within 64

  f32x4 acc[4][4];
#pragma unroll
  for (int i = 0; i < 4; ++i)
#pragma unroll
    for (int j = 0; j < 4; ++j)
      acc[i][j] = (f32x4)(0.0f);

  for (int k0 = 0; k0 < IN_F; k0 += BK) {
#pragma unroll
    for (int i = 0; i < 4; ++i) {
      const int chunk = wv * 4 + i;          // wave-uniform
      const int row   = chunk * 8 + srow;    // 0..127
      const unsigned short* ga = A + (size_t)(m0 + row) * IN_F + (k0 + scol);
      const unsigned short* gb = B + (size_t)(n0 + row) * IN_F + (k0 + scol);
      __builtin_amdgcn_global_load_lds((const GLOBAL_AS unsigned int*)ga,
                                       (LDS_AS unsigned int*)(As + chunk * 512),
                                       16, 0, 0);
      __builtin_amdgcn_global_load_lds((const GLOBAL_AS unsigned int*)gb,
                                       (LDS_AS unsigned int*)(Bs + chunk * 512),
                                       16, 0, 0);
    }
    __syncthreads();

#pragma unroll
    for (int ks = 0; ks < BK; ks += 32) {
      const int kcbase = ks >> 3;  // 0 or 4: logical 16B-chunk base index
      bf16x8 af[4], bfr[4];
#pragma unroll
      for (int i = 0; i < 4; ++i) {
        // logical chunk = kcbase + quad; physical = (kcbase+quad) ^ (r&7), r&7 == lr&7
        const int pc = ((kcbase + quad) ^ (lr & 7)) * 8;
        af[i]  = *(const bf16x8*)(As + (wm * 64 + i * 16 + lr) * BK + pc);
        bfr[i] = *(const bf16x8*)(Bs + (wn * 64 + i * 16 + lr) * BK + pc);
      }
#pragma unroll
      for (int i = 0; i < 4; ++i)
#pragma unroll
        for (int j = 0; j < 4; ++j)
          acc[i][j] = __builtin_amdgcn_mfma_f32_16x16x32_bf16(af[i], bfr[j], acc[i][j], 0, 0, 0);
    }
    __syncthreads();
  }

  // epilogue: C/D layout col = lane&15, row = quad*4 + reg (m89/m91-verified)
#pragma unroll
  for (int i = 0; i < 4; ++i) {
    const int mrow = m0 + wm * 64 + i * 16 + quad * 4;
#pragma unroll
    for (int j = 0; j < 4; ++j) {
      const int ncol = n0 + wn * 64 + j * 16 + lr;
      float* cp = C + (size_t)mrow * OUT_F + ncol;
#pragma unroll
      for (int r = 0; r < 4; ++r)
        cp[(size_t)r * OUT_F] = acc[i][j][r];
    }
  }
}

extern "C" void kernel_launch(void* const* d_in, const int* in_sizes, int n_in,
                              void* d_out, int out_size, void* d_ws, size_t ws_size,
                              hipStream_t stream) {
  const float* x       = (const float*)d_in[0];   // [4,2048,4096] f32
  const int*   ternary = (const int*)d_in[1];     // [4096,4096] int {-1,0,1}
  const float* scales  = (const float*)d_in[2];   // [131072] f32
  float* out = (float*)d_out;                     // [4,2048,4096] f32

  unsigned short* xb = (unsigned short*)d_ws;                 // 67.1 MB
  unsigned short* wb = xb + (size_t)MROWS * IN_F;             // +33.6 MB

  cvt_x_kernel<<<(MROWS * IN_F) / 8 / 256, 256, 0, stream>>>(x, xb);
  dequant_w_kernel<<<(OUT_F * IN_F) / 8 / 256, 256, 0, stream>>>(ternary, scales, wb);

  dim3 grid(OUT_F / BN, MROWS / BM);  // (32, 64) = 2048 blocks
  gemm_bt_kernel<<<grid, 256, 0, stream>>>(xb, wb, out);
}

// Round 3
// 555.829 us; speedup vs baseline: 1.1459x; 1.0837x over previous
//
#include <hip/hip_runtime.h>

// SPRTFlipLinear: y = x @ W^T, W = ternary * per-128-group scales.
// M=8192, N=4096, K=4096. 274.9 GFLOP/call.
// R2: switch GEMM to v_mfma_f32_32x32x16_bf16 (2x2 tiles/wave) — 17% fewer
//     matrix-pipe cycles (m119: 8.07 cyc vs 2x4.85) and half the MFMA issue
//     slots. Converters merged into one launch. XOR-swizzled LDS kept (R1: 0 conflicts).

#define IN_F  4096
#define OUT_F 4096
#define MROWS 8192
#define GROUP 128

#define BM 128
#define BN 128
#define BK 64

using bf16x8  = __attribute__((ext_vector_type(8))) __bf16;
using f32x16  = __attribute__((ext_vector_type(16))) float;

#define GLOBAL_AS __attribute__((address_space(1)))
#define LDS_AS    __attribute__((address_space(3)))

__device__ __forceinline__ unsigned short f2bf(float f) {
  unsigned int u = __float_as_uint(f);
  u += 0x7fffu + ((u >> 16) & 1u);
  return (unsigned short)(u >> 16);
}

#define CVT_BLOCKS ((MROWS * IN_F) / 8 / 256)   // 16384
#define DQ_BLOCKS  ((OUT_F * IN_F) / 8 / 256)   // 8192

// merged: blocks [0, CVT_BLOCKS) convert x f32->bf16; rest dequant ternary->bf16
__global__ void prep_kernel(const float* __restrict__ x, unsigned short* __restrict__ xb,
                            const int* __restrict__ t, const float* __restrict__ s,
                            unsigned short* __restrict__ wb) {
  int b = blockIdx.x;
  if (b < CVT_BLOCKS) {
    const int i = (b * 256 + threadIdx.x) * 8;
    const float4 a0 = *(const float4*)(x + i);
    const float4 a1 = *(const float4*)(x + i + 4);
    union { unsigned short u[8]; uint4 v; } o;
    o.u[0] = f2bf(a0.x); o.u[1] = f2bf(a0.y); o.u[2] = f2bf(a0.z); o.u[3] = f2bf(a0.w);
    o.u[4] = f2bf(a1.x); o.u[5] = f2bf(a1.y); o.u[6] = f2bf(a1.z); o.u[7] = f2bf(a1.w);
    *(uint4*)(xb + i) = o.v;
  } else {
    const int i = ((b - CVT_BLOCKS) * 256 + threadIdx.x) * 8;
    const float sc = s[i >> 7];  // GROUP=128
    const int4 t0 = *(const int4*)(t + i);
    const int4 t1 = *(const int4*)(t + i + 4);
    union { unsigned short u[8]; uint4 v; } o;
    o.u[0] = f2bf((float)t0.x * sc); o.u[1] = f2bf((float)t0.y * sc);
    o.u[2] = f2bf((float)t0.z * sc); o.u[3] = f2bf((float)t0.w * sc);
    o.u[4] = f2bf((float)t1.x * sc); o.u[5] = f2bf((float)t1.y * sc);
    o.u[6] = f2bf((float)t1.z * sc); o.u[7] = f2bf((float)t1.w * sc);
    *(uint4*)(wb + i) = o.v;
  }
}

// C[M][N] = A[M][K]*B[N][K]^T, bf16 in fp32 out.
// 128x128 block, BK=64, 4 waves 2x2, 64x64/wave as 2x2 of 32x32x16 MFMA.
// LDS XOR swizzle: 16B chunk kc of row r at physical chunk kc^(r&7); staging
// permutes per-lane global source (global_load_lds dest fixed at base+lane*16).
__global__ __launch_bounds__(256) void gemm_bt_kernel(const unsigned short* __restrict__ A,
                                                      const unsigned short* __restrict__ B,
                                                      float* __restrict__ C) {
  __shared__ unsigned short As[BM * BK];  // 16 KB
  __shared__ unsigned short Bs[BN * BK];  // 16 KB

  const int tid  = threadIdx.x;
  const int lane = tid & 63;
  const int wv   = tid >> 6;
  const int wm   = wv & 1;
  const int wn   = wv >> 1;
  const int r32  = lane & 31;    // fragment row within 32
  const int half = lane >> 5;    // k-half (0/1)

  const int m0 = blockIdx.y * BM;
  const int n0 = blockIdx.x * BN;

  // staging: chunk = 1024B = 8 rows x 128B; lane slot = (srow, lane&7);
  // slot must hold global k-chunk (lane&7)^srow (swizzle).
  const int srow = lane >> 3;
  const int scol = ((lane & 7) ^ srow) * 8;

  f32x16 acc[2][2];
#pragma unroll
  for (int i = 0; i < 2; ++i)
#pragma unroll
    for (int j = 0; j < 2; ++j)
      acc[i][j] = (f32x16)(0.0f);

  for (int k0 = 0; k0 < IN_F; k0 += BK) {
#pragma unroll
    for (int i = 0; i < 4; ++i) {
      const int chunk = wv * 4 + i;          // wave-uniform
      const int row   = chunk * 8 + srow;    // 0..127
      const unsigned short* ga = A + (size_t)(m0 + row) * IN_F + (k0 + scol);
      const unsigned short* gb = B + (size_t)(n0 + row) * IN_F + (k0 + scol);
      __builtin_amdgcn_global_load_lds((const GLOBAL_AS unsigned int*)ga,
                                       (LDS_AS unsigned int*)(As + chunk * 512),
                                       16, 0, 0);
      __builtin_amdgcn_global_load_lds((const GLOBAL_AS unsigned int*)gb,
                                       (LDS_AS unsigned int*)(Bs + chunk * 512),
                                       16, 0, 0);
    }
    __syncthreads();

#pragma unroll
    for (int ks = 0; ks < BK; ks += 16) {
      // A frag (32x32x16): m = r32, k = half*8 + j; logical chunk = ks/8 + half
      // physical chunk = logical ^ (row&7); row&7 == lane&7 (tile offsets %8==0)
      const int pc = (((ks >> 3) + half) ^ (lane & 7)) * 8;
      bf16x8 af[2], bfr[2];
#pragma unroll
      for (int t = 0; t < 2; ++t) {
        af[t]  = *(const bf16x8*)(As + (wm * 64 + t * 32 + r32) * BK + pc);
        bfr[t] = *(const bf16x8*)(Bs + (wn * 64 + t * 32 + r32) * BK + pc);
      }
#pragma unroll
      for (int i = 0; i < 2; ++i)
#pragma unroll
        for (int j = 0; j < 2; ++j)
          acc[i][j] = __builtin_amdgcn_mfma_f32_32x32x16_bf16(af[i], bfr[j], acc[i][j], 0, 0, 0);
    }
    __syncthreads();
  }

  // C/D layout (m74/m101-verified): col = lane&31, row = (reg&3)+8*(reg>>2)+4*(lane>>5)
#pragma unroll
  for (int i = 0; i < 2; ++i)
#pragma unroll
    for (int j = 0; j < 2; ++j) {
      const int ncol = n0 + wn * 64 + j * 32 + r32;
      const int mbase = m0 + wm * 64 + i * 32 + 4 * half;
#pragma unroll
      for (int r = 0; r < 16; ++r) {
        const int mrow = mbase + (r & 3) + 8 * (r >> 2);
        C[(size_t)mrow * OUT_F + ncol] = acc[i][j][r];
      }
    }
}

extern "C" void kernel_launch(void* const* d_in, const int* in_sizes, int n_in,
                              void* d_out, int out_size, void* d_ws, size_t ws_size,
                              hipStream_t stream) {
  const float* x       = (const float*)d_in[0];   // [4,2048,4096] f32
  const int*   ternary = (const int*)d_in[1];     // [4096,4096] int {-1,0,1}
  const float* scales  = (const float*)d_in[2];   // [131072] f32
  float* out = (float*)d_out;                     // [4,2048,4096] f32

  unsigned short* xb = (unsigned short*)d_ws;                 // 67.1 MB
  unsigned short* wb = xb + (size_t)MROWS * IN_F;             // +33.6 MB

  prep_kernel<<<CVT_BLOCKS + DQ_BLOCKS, 256, 0, stream>>>(x, xb, ternary, scales, wb);

  dim3 grid(OUT_F / BN, MROWS / BM);  // (32, 64) = 2048 blocks
  gemm_bt_kernel<<<grid, 256, 0, stream>>>(xb, wb, out);
}

// Round 4
// 521.625 us; speedup vs baseline: 1.2210x; 1.0656x over previous
//
#include <hip/hip_runtime.h>

// SPRTFlipLinear: y = x @ W^T, W = ternary * per-128-group scales.
// M=8192, N=4096, K=4096. 274.9 GFLOP/call.
// R3: block tile 256x128, wave tile 128x64 (4x2 of 32x32x16 MFMA) to cut
//     LDS-read traffic from 1.0 to 0.75 b128/MFMA (LDS-read floor was the
//     binding constraint: ~164us vs 110us MFMA floor at R2's ratio).

#define IN_F  4096
#define OUT_F 4096
#define MROWS 8192
#define GROUP 128

#define BM 256
#define BN 128
#define BK 64

using bf16x8  = __attribute__((ext_vector_type(8))) __bf16;
using f32x16  = __attribute__((ext_vector_type(16))) float;

#define GLOBAL_AS __attribute__((address_space(1)))
#define LDS_AS    __attribute__((address_space(3)))

__device__ __forceinline__ unsigned short f2bf(float f) {
  unsigned int u = __float_as_uint(f);
  u += 0x7fffu + ((u >> 16) & 1u);
  return (unsigned short)(u >> 16);
}

#define CVT_BLOCKS ((MROWS * IN_F) / 8 / 256)   // 16384
#define DQ_BLOCKS  ((OUT_F * IN_F) / 8 / 256)   // 8192

// blocks [0, CVT_BLOCKS) convert x f32->bf16; rest dequant ternary->bf16
__global__ void prep_kernel(const float* __restrict__ x, unsigned short* __restrict__ xb,
                            const int* __restrict__ t, const float* __restrict__ s,
                            unsigned short* __restrict__ wb) {
  int b = blockIdx.x;
  if (b < CVT_BLOCKS) {
    const int i = (b * 256 + threadIdx.x) * 8;
    const float4 a0 = *(const float4*)(x + i);
    const float4 a1 = *(const float4*)(x + i + 4);
    union { unsigned short u[8]; uint4 v; } o;
    o.u[0] = f2bf(a0.x); o.u[1] = f2bf(a0.y); o.u[2] = f2bf(a0.z); o.u[3] = f2bf(a0.w);
    o.u[4] = f2bf(a1.x); o.u[5] = f2bf(a1.y); o.u[6] = f2bf(a1.z); o.u[7] = f2bf(a1.w);
    *(uint4*)(xb + i) = o.v;
  } else {
    const int i = ((b - CVT_BLOCKS) * 256 + threadIdx.x) * 8;
    const float sc = s[i >> 7];  // GROUP=128
    const int4 t0 = *(const int4*)(t + i);
    const int4 t1 = *(const int4*)(t + i + 4);
    union { unsigned short u[8]; uint4 v; } o;
    o.u[0] = f2bf((float)t0.x * sc); o.u[1] = f2bf((float)t0.y * sc);
    o.u[2] = f2bf((float)t0.z * sc); o.u[3] = f2bf((float)t0.w * sc);
    o.u[4] = f2bf((float)t1.x * sc); o.u[5] = f2bf((float)t1.y * sc);
    o.u[6] = f2bf((float)t1.z * sc); o.u[7] = f2bf((float)t1.w * sc);
    *(uint4*)(wb + i) = o.v;
  }
}

// C[M][N] = A[M][K]*B[N][K]^T, bf16 in fp32 out.
// 256x128 block, BK=64, 4 waves in 2x2 grid, 128x64 per wave (4x2 of 32x32x16).
// LDS XOR swizzle: 16B chunk kc of row r at physical chunk kc^(r&7); staging
// permutes per-lane GLOBAL source (global_load_lds dest fixed at base+lane*16).
__global__ __launch_bounds__(256, 2) void gemm_bt_kernel(const unsigned short* __restrict__ A,
                                                         const unsigned short* __restrict__ B,
                                                         float* __restrict__ C) {
  __shared__ unsigned short As[BM * BK];  // 32 KB, 32 chunks of 1KB (8 rows x 128B)
  __shared__ unsigned short Bs[BN * BK];  // 16 KB, 16 chunks

  const int tid  = threadIdx.x;
  const int lane = tid & 63;
  const int wv   = tid >> 6;
  const int wm   = wv & 1;       // M half (0..1), 128 rows each
  const int wn   = wv >> 1;      // N half (0..1), 64 cols each
  const int r32  = lane & 31;
  const int half = lane >> 5;    // k-half of fragment

  const int m0 = blockIdx.y * BM;
  const int n0 = blockIdx.x * BN;

  // staging: lane slot = (srow, lane&7) within its chunk; slot holds global
  // k-chunk (lane&7)^srow (the XOR swizzle realized on the global side).
  const int srow = lane >> 3;
  const int scol = ((lane & 7) ^ srow) * 8;

  f32x16 acc[4][2];
#pragma unroll
  for (int i = 0; i < 4; ++i)
#pragma unroll
    for (int j = 0; j < 2; ++j)
      acc[i][j] = (f32x16)(0.0f);

  for (int k0 = 0; k0 < IN_F; k0 += BK) {
    // A: 32 chunks, 8 per wave; B: 16 chunks, 4 per wave
#pragma unroll
    for (int i = 0; i < 8; ++i) {
      const int chunk = wv * 8 + i;
      const int row   = chunk * 8 + srow;
      const unsigned short* ga = A + (size_t)(m0 + row) * IN_F + (k0 + scol);
      __builtin_amdgcn_global_load_lds((const GLOBAL_AS unsigned int*)ga,
                                       (LDS_AS unsigned int*)(As + chunk * 512),
                                       16, 0, 0);
    }
#pragma unroll
    for (int i = 0; i < 4; ++i) {
      const int chunk = wv * 4 + i;
      const int row   = chunk * 8 + srow;
      const unsigned short* gb = B + (size_t)(n0 + row) * IN_F + (k0 + scol);
      __builtin_amdgcn_global_load_lds((const GLOBAL_AS unsigned int*)gb,
                                       (LDS_AS unsigned int*)(Bs + chunk * 512),
                                       16, 0, 0);
    }
    __syncthreads();

#pragma unroll
    for (int ks = 0; ks < BK; ks += 16) {
      // logical chunk = ks/8 + half; physical = logical ^ (row&7), row&7==lane&7
      const int pc = (((ks >> 3) + half) ^ (lane & 7)) * 8;
      bf16x8 af[4], bfr[2];
#pragma unroll
      for (int t = 0; t < 4; ++t)
        af[t] = *(const bf16x8*)(As + (wm * 128 + t * 32 + r32) * BK + pc);
#pragma unroll
      for (int t = 0; t < 2; ++t)
        bfr[t] = *(const bf16x8*)(Bs + (wn * 64 + t * 32 + r32) * BK + pc);
#pragma unroll
      for (int i = 0; i < 4; ++i)
#pragma unroll
        for (int j = 0; j < 2; ++j)
          acc[i][j] = __builtin_amdgcn_mfma_f32_32x32x16_bf16(af[i], bfr[j], acc[i][j], 0, 0, 0);
    }
    __syncthreads();
  }

  // C/D layout: col = lane&31, row = (reg&3)+8*(reg>>2)+4*(lane>>5)
#pragma unroll
  for (int i = 0; i < 4; ++i)
#pragma unroll
    for (int j = 0; j < 2; ++j) {
      const int ncol  = n0 + wn * 64 + j * 32 + r32;
      const int mbase = m0 + wm * 128 + i * 32 + 4 * half;
#pragma unroll
      for (int r = 0; r < 16; ++r) {
        const int mrow = mbase + (r & 3) + 8 * (r >> 2);
        C[(size_t)mrow * OUT_F + ncol] = acc[i][j][r];
      }
    }
}

extern "C" void kernel_launch(void* const* d_in, const int* in_sizes, int n_in,
                              void* d_out, int out_size, void* d_ws, size_t ws_size,
                              hipStream_t stream) {
  const float* x       = (const float*)d_in[0];   // [4,2048,4096] f32
  const int*   ternary = (const int*)d_in[1];     // [4096,4096] int {-1,0,1}
  const float* scales  = (const float*)d_in[2];   // [131072] f32
  float* out = (float*)d_out;                     // [4,2048,4096] f32

  unsigned short* xb = (unsigned short*)d_ws;                 // 67.1 MB
  unsigned short* wb = xb + (size_t)MROWS * IN_F;             // +33.6 MB

  prep_kernel<<<CVT_BLOCKS + DQ_BLOCKS, 256, 0, stream>>>(x, xb, ternary, scales, wb);

  dim3 grid(OUT_F / BN, MROWS / BM);  // (32, 32) = 1024 blocks
  gemm_bt_kernel<<<grid, 256, 0, stream>>>(xb, wb, out);
}